// Round 1
// 1656.170 us; speedup vs baseline: 1.3162x; 1.3162x over previous
//
#include <hip/hip_runtime.h>

// LightGCN propagation: 3 sparse layers over a fixed bipartite graph.
// R3: replace flat counting-sort (hist: 10M device atomics; scatter: 10M
// device atomics + 8x write amplification, 620MB HBM writes for 80MB payload,
// ~560us) with a two-level bucket sort:
//   coarse_hist -> scan_buckets -> bin_kernel (LDS-reserved, bucket-grouped
//   writes) -> finalize_kernel (per-bucket CSR via LDS cursors, L2-resident
//   scatter window). ~360K device atomics total, ~1x write amplification.
// Layer kernels unchanged from R2 (one wave per row, gather unroll x8).

#define EMB 64
// 512 rows per bucket: localrow = 9 bits, col < 300000 -> 19 bits, packs in 28.
#define BSH 9
#define BROWS 512

__global__ __launch_bounds__(256) void coarse_hist(const int* __restrict__ rows,
                                                   int* __restrict__ cnt, int nnz, int NB) {
    __shared__ int lcnt[1024];
    int t = threadIdx.x;
    for (int k = t; k < 1024; k += 256) lcnt[k] = 0;
    __syncthreads();
    int stride = gridDim.x * 256;
    for (int i = blockIdx.x * 256 + t; i < nnz; i += stride)
        atomicAdd(&lcnt[rows[i] >> BSH], 1);
    __syncthreads();
    for (int k = t; k < 1024; k += 256) {
        int c = lcnt[k];
        if (k < NB && c > 0) atomicAdd(&cnt[k], c);
    }
}

// single block: exclusive scan over NB (<=1024) bucket counts
__global__ void scan_buckets(const int* __restrict__ cnt, int* __restrict__ base,
                             int* __restrict__ cursor, int* __restrict__ row_ptr,
                             int NB, int N) {
    __shared__ int sblk[256];
    int t = threadIdx.x;
    int a[4]; int tsum = 0;
#pragma unroll
    for (int k = 0; k < 4; ++k) { int b = t * 4 + k; a[k] = (b < NB) ? cnt[b] : 0; tsum += a[k]; }
    int x = tsum; sblk[t] = x; __syncthreads();
    for (int off = 1; off < 256; off <<= 1) {
        int y = (t >= off) ? sblk[t - off] : 0;
        __syncthreads();
        x += y; sblk[t] = x; __syncthreads();
    }
    int run = x - tsum;   // exclusive prefix for this thread's 4 entries
#pragma unroll
    for (int k = 0; k < 4; ++k) {
        int b = t * 4 + k;
        if (b < NB) { base[b] = run; cursor[b] = run; }
        run += a[k];
    }
    if (t == 255) { base[NB] = x; row_ptr[N] = x; }   // x == nnz
}

// Bucket-grouped binning. Per block: count chunk's edges per bucket in LDS,
// reserve one contiguous range per touched bucket (1 global atomic each),
// then place records. Writes to a bucket form a ~100-200B run reserved
// moments earlier -> full lines, L2 write-combined.
#define BIN_VPT 64   // edges per thread; chunk = 16384
__global__ __launch_bounds__(256) void bin_kernel(
    const int* __restrict__ rows, const int* __restrict__ cols,
    const float* __restrict__ vals, int* __restrict__ cursor,
    int2* __restrict__ binned, int nnz, int NB)
{
    __shared__ int lcnt[1024];
    __shared__ int gbase[1024];
    int t = threadIdx.x;
    int base0 = blockIdx.x * (256 * BIN_VPT);
    for (int k = t; k < 1024; k += 256) lcnt[k] = 0;
    __syncthreads();
#pragma unroll 4
    for (int j = 0; j < BIN_VPT; ++j) {
        int i = base0 + j * 256 + t;
        if (i < nnz) atomicAdd(&lcnt[rows[i] >> BSH], 1);
    }
    __syncthreads();
    for (int k = t; k < 1024; k += 256) {
        int c = lcnt[k];
        if (k < NB && c > 0) gbase[k] = atomicAdd(&cursor[k], c);
        lcnt[k] = 0;
    }
    __syncthreads();
#pragma unroll 4
    for (int j = 0; j < BIN_VPT; ++j) {
        int i = base0 + j * 256 + t;
        if (i < nnz) {
            int r = rows[i];
            int b = r >> BSH;
            int lp = atomicAdd(&lcnt[b], 1);
            binned[gbase[b] + lp] =
                make_int2(((r - (b << BSH)) << 19) | cols[i], __float_as_int(vals[i]));
        }
    }
}

// One WG per bucket: LDS row-hist + scan -> row_ptr; then scatter records to
// final CSR slots via LDS cursors. Scatter window = this bucket's CSR segment
// (~150-200KB), L2-resident -> ~1x write amplification. Zero global atomics.
__global__ __launch_bounds__(256) void finalize_kernel(
    const int* __restrict__ base, const int2* __restrict__ binned,
    int* __restrict__ row_ptr, int2* __restrict__ edges, int N)
{
    __shared__ int lhist[BROWS];
    __shared__ int lpref[BROWS];
    __shared__ int sblk[256];
    int b = blockIdx.x;
    int t = threadIdx.x;
    int s = base[b], e = base[b + 1];
    lhist[t] = 0; lhist[t + 256] = 0;
    __syncthreads();
    for (int i = s + t; i < e; i += 256)
        atomicAdd(&lhist[binned[i].x >> 19], 1);
    __syncthreads();
    // exclusive scan over 512 row counts (2 per thread)
    int a0 = lhist[2 * t], a1 = lhist[2 * t + 1];
    int tsum = a0 + a1;
    int x = tsum; sblk[t] = x; __syncthreads();
    for (int off = 1; off < 256; off <<= 1) {
        int y = (t >= off) ? sblk[t - off] : 0;
        __syncthreads();
        x += y; sblk[t] = x; __syncthreads();
    }
    int excl = x - tsum;
    lpref[2 * t] = excl; lpref[2 * t + 1] = excl + a0;
    __syncthreads();
    for (int lr = t; lr < BROWS; lr += 256) {
        int gr = (b << BSH) + lr;
        int slot = s + lpref[lr];
        if (gr < N) row_ptr[gr] = slot;
        lhist[lr] = slot;   // reuse as global-slot cursor
    }
    __syncthreads();
    for (int i = s + t; i < e; i += 256) {
        int2 rec = binned[i];
        int lr = rec.x >> 19;
        int pos = atomicAdd(&lhist[lr], 1);
        edges[pos] = make_int2(rec.x & 0x7FFFF, rec.y);
    }
}

__device__ __forceinline__ const float* col_ptr(int c, const float* ue, const float* ie, int nu) {
    return (c < nu) ? (ue + (size_t)c * EMB) : (ie + ((size_t)c - nu) * EMB);
}

// One wave per row; lane = dim. Unrolled x8: 8 independent 256B gathers in
// flight per wave to cover HBM latency.
// MODE 0: first layer (reads ue/ie directly, inits acc = e0 + sum)
// MODE 1: middle layer (acc += sum)
// MODE 2: last layer   (acc = (acc + sum) * 0.25, no embout write)
template<int MODE>
__global__ __launch_bounds__(256) void layer_kernel(
    const int* __restrict__ row_ptr, const int2* __restrict__ edges,
    const float* __restrict__ embin, const float* __restrict__ ue,
    const float* __restrict__ ie, float* __restrict__ embout,
    float* __restrict__ acc, int N, int nu)
{
    int row  = (int)((blockIdx.x * blockDim.x + threadIdx.x) >> 6);
    int lane = threadIdx.x & 63;
    if (row >= N) return;
    int s = row_ptr[row], e = row_ptr[row + 1];
    float sum0 = 0.f, sum1 = 0.f, sum2 = 0.f, sum3 = 0.f;
    int i = s;
    for (; i + 8 <= e; i += 8) {
        int2 c0 = edges[i+0], c1 = edges[i+1], c2 = edges[i+2], c3 = edges[i+3];
        int2 c4 = edges[i+4], c5 = edges[i+5], c6 = edges[i+6], c7 = edges[i+7];
        float g0, g1, g2, g3, g4, g5, g6, g7;
        if (MODE == 0) {
            g0 = col_ptr(c0.x, ue, ie, nu)[lane];
            g1 = col_ptr(c1.x, ue, ie, nu)[lane];
            g2 = col_ptr(c2.x, ue, ie, nu)[lane];
            g3 = col_ptr(c3.x, ue, ie, nu)[lane];
            g4 = col_ptr(c4.x, ue, ie, nu)[lane];
            g5 = col_ptr(c5.x, ue, ie, nu)[lane];
            g6 = col_ptr(c6.x, ue, ie, nu)[lane];
            g7 = col_ptr(c7.x, ue, ie, nu)[lane];
        } else {
            g0 = embin[(size_t)c0.x * EMB + lane];
            g1 = embin[(size_t)c1.x * EMB + lane];
            g2 = embin[(size_t)c2.x * EMB + lane];
            g3 = embin[(size_t)c3.x * EMB + lane];
            g4 = embin[(size_t)c4.x * EMB + lane];
            g5 = embin[(size_t)c5.x * EMB + lane];
            g6 = embin[(size_t)c6.x * EMB + lane];
            g7 = embin[(size_t)c7.x * EMB + lane];
        }
        sum0 = fmaf(__int_as_float(c0.y), g0, sum0);
        sum1 = fmaf(__int_as_float(c1.y), g1, sum1);
        sum2 = fmaf(__int_as_float(c2.y), g2, sum2);
        sum3 = fmaf(__int_as_float(c3.y), g3, sum3);
        sum0 = fmaf(__int_as_float(c4.y), g4, sum0);
        sum1 = fmaf(__int_as_float(c5.y), g5, sum1);
        sum2 = fmaf(__int_as_float(c6.y), g6, sum2);
        sum3 = fmaf(__int_as_float(c7.y), g7, sum3);
    }
    for (; i < e; ++i) {
        int2 cv = edges[i];
        float g = (MODE == 0) ? col_ptr(cv.x, ue, ie, nu)[lane]
                              : embin[(size_t)cv.x * EMB + lane];
        sum0 = fmaf(__int_as_float(cv.y), g, sum0);
    }
    float sum = (sum0 + sum1) + (sum2 + sum3);
    size_t idx = (size_t)row * EMB + lane;
    if (MODE != 2) embout[idx] = sum;
    if (MODE == 0) {
        float base = (row < nu) ? ue[idx] : ie[idx - (size_t)nu * EMB];
        acc[idx] = base + sum;
    } else if (MODE == 1) {
        acc[idx] += sum;
    } else {
        acc[idx] = (acc[idx] + sum) * 0.25f;
    }
}

extern "C" void kernel_launch(void* const* d_in, const int* in_sizes, int n_in,
                              void* d_out, int out_size, void* d_ws, size_t ws_size,
                              hipStream_t stream) {
    const float* ue   = (const float*)d_in[0];
    const float* ie   = (const float*)d_in[1];
    const float* vals = (const float*)d_in[2];
    const int*   rows = (const int*)d_in[3];
    const int*   cols = (const int*)d_in[4];

    int nu  = in_sizes[0] / EMB;
    int ni  = in_sizes[1] / EMB;
    int N   = nu + ni;
    int nnz = in_sizes[2];
    int M   = N + 1;
    int NB  = (N + BROWS - 1) >> BSH;   // 586 buckets for N=300000 (<=1024)

    // workspace carve-out (256B aligned)
    char*  w   = (char*)d_ws;
    size_t off = 0;
    auto alloc = [&](size_t bytes) -> void* {
        void* p = w + off;
        off = (off + bytes + 255) & ~(size_t)255;
        return p;
    };
    float* embA    = (float*)alloc((size_t)N * EMB * sizeof(float));
    float* embB    = (float*)alloc((size_t)N * EMB * sizeof(float));
    int2*  edges   = (int2*) alloc((size_t)nnz * sizeof(int2));
    int*   cnt     = (int*)  alloc(1024 * sizeof(int));
    int*   base    = (int*)  alloc(1025 * sizeof(int));
    int*   cursor  = (int*)  alloc(1024 * sizeof(int));
    int*   row_ptr = (int*)  alloc((size_t)M * sizeof(int));
    float* acc     = (float*)d_out;   // accumulator lives in the output buffer

    // binned records (nnz * 8B = 80MB) alias embA+embB (153.6MB), which are
    // dead until layer0 runs (after finalize_kernel has consumed binned).
    int2* binned = (int2*)embA;

    hipMemsetAsync(cnt, 0, 1024 * sizeof(int), stream);

    coarse_hist<<<512, 256, 0, stream>>>(rows, cnt, nnz, NB);
    scan_buckets<<<1, 256, 0, stream>>>(cnt, base, cursor, row_ptr, NB, N);

    int bgrid = (nnz + 256 * BIN_VPT - 1) / (256 * BIN_VPT);
    bin_kernel<<<bgrid, 256, 0, stream>>>(rows, cols, vals, cursor, binned, nnz, NB);
    finalize_kernel<<<NB, 256, 0, stream>>>(base, binned, row_ptr, edges, N);

    int lgrid = (N + 3) / 4;   // 4 waves (rows) per 256-thread block
    layer_kernel<0><<<lgrid, 256, 0, stream>>>(row_ptr, edges, nullptr, ue, ie, embA, acc, N, nu);
    layer_kernel<1><<<lgrid, 256, 0, stream>>>(row_ptr, edges, embA, ue, ie, embB, acc, N, nu);
    layer_kernel<2><<<lgrid, 256, 0, stream>>>(row_ptr, edges, embB, ue, ie, nullptr, acc, N, nu);
}

// Round 3
// 1551.682 us; speedup vs baseline: 1.4048x; 1.0673x over previous
//
#include <hip/hip_runtime.h>

// LightGCN propagation: 3 sparse layers over a fixed bipartite graph.
// R5 = R4 resubmitted verbatim (R4 bench died on container acquisition, not
// kernel error; source re-audited for OOB/hang hazards - none found).
// R4 changes vs R3:
//  (a) 16-lane x float4 gathers: one VMEM instr fetches 4 embedding rows
//      (4 edges) -> 4x fewer gather/addr instrs (R3 was VALUBusy=61%).
//      Cross-group reduce via shfl_xor(16,32), 8 ops per row.
//  (b) user/item phase split per layer: user rows gather only the item
//      half (25.6MB), item rows only the user half (51.2MB) -> smaller
//      L2 working set than the interleaved 76.8MB. Also kills the
//      col_ptr branch in layer 0.
// Preprocessing (two-level bucket sort) unchanged from R3.

#define EMB 64
// 512 rows per bucket: localrow = 9 bits, col < 300000 -> 19 bits, packs in 28.
#define BSH 9
#define BROWS 512

__global__ __launch_bounds__(256) void coarse_hist(const int* __restrict__ rows,
                                                   int* __restrict__ cnt, int nnz, int NB) {
    __shared__ int lcnt[1024];
    int t = threadIdx.x;
    for (int k = t; k < 1024; k += 256) lcnt[k] = 0;
    __syncthreads();
    int stride = gridDim.x * 256;
    for (int i = blockIdx.x * 256 + t; i < nnz; i += stride)
        atomicAdd(&lcnt[rows[i] >> BSH], 1);
    __syncthreads();
    for (int k = t; k < 1024; k += 256) {
        int c = lcnt[k];
        if (k < NB && c > 0) atomicAdd(&cnt[k], c);
    }
}

// single block: exclusive scan over NB (<=1024) bucket counts
__global__ void scan_buckets(const int* __restrict__ cnt, int* __restrict__ base,
                             int* __restrict__ cursor, int* __restrict__ row_ptr,
                             int NB, int N) {
    __shared__ int sblk[256];
    int t = threadIdx.x;
    int a[4]; int tsum = 0;
#pragma unroll
    for (int k = 0; k < 4; ++k) { int b = t * 4 + k; a[k] = (b < NB) ? cnt[b] : 0; tsum += a[k]; }
    int x = tsum; sblk[t] = x; __syncthreads();
    for (int off = 1; off < 256; off <<= 1) {
        int y = (t >= off) ? sblk[t - off] : 0;
        __syncthreads();
        x += y; sblk[t] = x; __syncthreads();
    }
    int run = x - tsum;   // exclusive prefix for this thread's 4 entries
#pragma unroll
    for (int k = 0; k < 4; ++k) {
        int b = t * 4 + k;
        if (b < NB) { base[b] = run; cursor[b] = run; }
        run += a[k];
    }
    if (t == 255) { base[NB] = x; row_ptr[N] = x; }   // x == nnz
}

// Bucket-grouped binning. Per block: count chunk's edges per bucket in LDS,
// reserve one contiguous range per touched bucket (1 global atomic each),
// then place records.
#define BIN_VPT 64   // edges per thread; chunk = 16384
__global__ __launch_bounds__(256) void bin_kernel(
    const int* __restrict__ rows, const int* __restrict__ cols,
    const float* __restrict__ vals, int* __restrict__ cursor,
    int2* __restrict__ binned, int nnz, int NB)
{
    __shared__ int lcnt[1024];
    __shared__ int gbase[1024];
    int t = threadIdx.x;
    int base0 = blockIdx.x * (256 * BIN_VPT);
    for (int k = t; k < 1024; k += 256) lcnt[k] = 0;
    __syncthreads();
#pragma unroll 4
    for (int j = 0; j < BIN_VPT; ++j) {
        int i = base0 + j * 256 + t;
        if (i < nnz) atomicAdd(&lcnt[rows[i] >> BSH], 1);
    }
    __syncthreads();
    for (int k = t; k < 1024; k += 256) {
        int c = lcnt[k];
        if (k < NB && c > 0) gbase[k] = atomicAdd(&cursor[k], c);
        lcnt[k] = 0;
    }
    __syncthreads();
#pragma unroll 4
    for (int j = 0; j < BIN_VPT; ++j) {
        int i = base0 + j * 256 + t;
        if (i < nnz) {
            int r = rows[i];
            int b = r >> BSH;
            int lp = atomicAdd(&lcnt[b], 1);
            binned[gbase[b] + lp] =
                make_int2(((r - (b << BSH)) << 19) | cols[i], __float_as_int(vals[i]));
        }
    }
}

// One WG per bucket: LDS row-hist + scan -> row_ptr; then scatter records to
// final CSR slots via LDS cursors (L2-resident window, zero global atomics).
__global__ __launch_bounds__(256) void finalize_kernel(
    const int* __restrict__ base, const int2* __restrict__ binned,
    int* __restrict__ row_ptr, int2* __restrict__ edges, int N)
{
    __shared__ int lhist[BROWS];
    __shared__ int lpref[BROWS];
    __shared__ int sblk[256];
    int b = blockIdx.x;
    int t = threadIdx.x;
    int s = base[b], e = base[b + 1];
    lhist[t] = 0; lhist[t + 256] = 0;
    __syncthreads();
    for (int i = s + t; i < e; i += 256)
        atomicAdd(&lhist[binned[i].x >> 19], 1);
    __syncthreads();
    int a0 = lhist[2 * t], a1 = lhist[2 * t + 1];
    int tsum = a0 + a1;
    int x = tsum; sblk[t] = x; __syncthreads();
    for (int off = 1; off < 256; off <<= 1) {
        int y = (t >= off) ? sblk[t - off] : 0;
        __syncthreads();
        x += y; sblk[t] = x; __syncthreads();
    }
    int excl = x - tsum;
    lpref[2 * t] = excl; lpref[2 * t + 1] = excl + a0;
    __syncthreads();
    for (int lr = t; lr < BROWS; lr += 256) {
        int gr = (b << BSH) + lr;
        int slot = s + lpref[lr];
        if (gr < N) row_ptr[gr] = slot;
        lhist[lr] = slot;   // reuse as global-slot cursor
    }
    __syncthreads();
    for (int i = s + t; i < e; i += 256) {
        int2 rec = binned[i];
        int lr = rec.x >> 19;
        int pos = atomicAdd(&lhist[lr], 1);
        edges[pos] = make_int2(rec.x & 0x7FFFF, rec.y);
    }
}

// One wave per row. 16-lane groups: group g (of 4) handles edge i+g, each
// lane holds 4 dims (float4). One gather instr = 4 edges' rows = 1KB.
// Main loop: 4 gathers (16 edges) in flight. Cross-group shfl_xor reduce
// at the end; group 0 does the 256B row write.
// MODE 0: acc = init + sum; embout = sum
// MODE 1: acc += sum;        embout = sum
// MODE 2: acc = (acc + sum) * 0.25, no embout
template<int MODE>
__global__ __launch_bounds__(256) void layer_kernel(
    const int* __restrict__ row_ptr, const int2* __restrict__ edges,
    const float4* __restrict__ src4, int cofs,
    const float4* __restrict__ init4,
    float4* __restrict__ embout4, float4* __restrict__ acc4,
    int row0, int nrows)
{
    int wid = (int)((blockIdx.x * blockDim.x + threadIdx.x) >> 6);
    if (wid >= nrows) return;
    int row  = row0 + wid;
    int lane = threadIdx.x & 63;
    int grp  = lane >> 4;
    int sub  = lane & 15;
    int s = row_ptr[row], e = row_ptr[row + 1];

    float4 a0 = make_float4(0.f, 0.f, 0.f, 0.f);
    float4 a1 = make_float4(0.f, 0.f, 0.f, 0.f);
    float4 a2 = make_float4(0.f, 0.f, 0.f, 0.f);
    float4 a3 = make_float4(0.f, 0.f, 0.f, 0.f);

    int i = s;
    for (; i + 16 <= e; i += 16) {
        int2 c0 = edges[i + grp];
        int2 c1 = edges[i + 4 + grp];
        int2 c2 = edges[i + 8 + grp];
        int2 c3 = edges[i + 12 + grp];
        float4 g0 = src4[(size_t)(c0.x - cofs) * 16 + sub];
        float4 g1 = src4[(size_t)(c1.x - cofs) * 16 + sub];
        float4 g2 = src4[(size_t)(c2.x - cofs) * 16 + sub];
        float4 g3 = src4[(size_t)(c3.x - cofs) * 16 + sub];
        float v0 = __int_as_float(c0.y);
        float v1 = __int_as_float(c1.y);
        float v2 = __int_as_float(c2.y);
        float v3 = __int_as_float(c3.y);
        a0.x = fmaf(v0, g0.x, a0.x); a0.y = fmaf(v0, g0.y, a0.y);
        a0.z = fmaf(v0, g0.z, a0.z); a0.w = fmaf(v0, g0.w, a0.w);
        a1.x = fmaf(v1, g1.x, a1.x); a1.y = fmaf(v1, g1.y, a1.y);
        a1.z = fmaf(v1, g1.z, a1.z); a1.w = fmaf(v1, g1.w, a1.w);
        a2.x = fmaf(v2, g2.x, a2.x); a2.y = fmaf(v2, g2.y, a2.y);
        a2.z = fmaf(v2, g2.z, a2.z); a2.w = fmaf(v2, g2.w, a2.w);
        a3.x = fmaf(v3, g3.x, a3.x); a3.y = fmaf(v3, g3.y, a3.y);
        a3.z = fmaf(v3, g3.z, a3.z); a3.w = fmaf(v3, g3.w, a3.w);
    }
    for (; i < e; i += 4) {
        int j = i + grp;
        if (j < e) {
            int2 cv = edges[j];
            float4 g = src4[(size_t)(cv.x - cofs) * 16 + sub];
            float v = __int_as_float(cv.y);
            a0.x = fmaf(v, g.x, a0.x); a0.y = fmaf(v, g.y, a0.y);
            a0.z = fmaf(v, g.z, a0.z); a0.w = fmaf(v, g.w, a0.w);
        }
    }

    float4 t;
    t.x = (a0.x + a1.x) + (a2.x + a3.x);
    t.y = (a0.y + a1.y) + (a2.y + a3.y);
    t.z = (a0.z + a1.z) + (a2.z + a3.z);
    t.w = (a0.w + a1.w) + (a2.w + a3.w);
    t.x += __shfl_xor(t.x, 16); t.x += __shfl_xor(t.x, 32);
    t.y += __shfl_xor(t.y, 16); t.y += __shfl_xor(t.y, 32);
    t.z += __shfl_xor(t.z, 16); t.z += __shfl_xor(t.z, 32);
    t.w += __shfl_xor(t.w, 16); t.w += __shfl_xor(t.w, 32);

    if (grp == 0) {
        size_t o = (size_t)row * 16 + sub;
        if (MODE != 2) embout4[o] = t;
        if (MODE == 0) {
            float4 b = init4[(size_t)wid * 16 + sub];
            b.x += t.x; b.y += t.y; b.z += t.z; b.w += t.w;
            acc4[o] = b;
        } else if (MODE == 1) {
            float4 r = acc4[o];
            r.x += t.x; r.y += t.y; r.z += t.z; r.w += t.w;
            acc4[o] = r;
        } else {
            float4 r = acc4[o];
            r.x = (r.x + t.x) * 0.25f; r.y = (r.y + t.y) * 0.25f;
            r.z = (r.z + t.z) * 0.25f; r.w = (r.w + t.w) * 0.25f;
            acc4[o] = r;
        }
    }
}

extern "C" void kernel_launch(void* const* d_in, const int* in_sizes, int n_in,
                              void* d_out, int out_size, void* d_ws, size_t ws_size,
                              hipStream_t stream) {
    const float* ue   = (const float*)d_in[0];
    const float* ie   = (const float*)d_in[1];
    const float* vals = (const float*)d_in[2];
    const int*   rows = (const int*)d_in[3];
    const int*   cols = (const int*)d_in[4];

    int nu  = in_sizes[0] / EMB;
    int ni  = in_sizes[1] / EMB;
    int N   = nu + ni;
    int nnz = in_sizes[2];
    int M   = N + 1;
    int NB  = (N + BROWS - 1) >> BSH;   // 586 buckets for N=300000 (<=1024)

    // workspace carve-out (256B aligned)
    char*  w   = (char*)d_ws;
    size_t off = 0;
    auto alloc = [&](size_t bytes) -> void* {
        void* p = w + off;
        off = (off + bytes + 255) & ~(size_t)255;
        return p;
    };
    float* embA    = (float*)alloc((size_t)N * EMB * sizeof(float));
    float* embB    = (float*)alloc((size_t)N * EMB * sizeof(float));
    int2*  edges   = (int2*) alloc((size_t)nnz * sizeof(int2));
    int*   cnt     = (int*)  alloc(1024 * sizeof(int));
    int*   base    = (int*)  alloc(1025 * sizeof(int));
    int*   cursor  = (int*)  alloc(1024 * sizeof(int));
    int*   row_ptr = (int*)  alloc((size_t)M * sizeof(int));
    float* acc     = (float*)d_out;   // accumulator lives in the output buffer

    // binned records (nnz * 8B = 80MB) alias embA+embB (153.6MB), which are
    // dead until layer0 runs (after finalize_kernel has consumed binned).
    int2* binned = (int2*)embA;

    hipMemsetAsync(cnt, 0, 1024 * sizeof(int), stream);

    coarse_hist<<<512, 256, 0, stream>>>(rows, cnt, nnz, NB);
    scan_buckets<<<1, 256, 0, stream>>>(cnt, base, cursor, row_ptr, NB, N);

    int bgrid = (nnz + 256 * BIN_VPT - 1) / (256 * BIN_VPT);
    bin_kernel<<<bgrid, 256, 0, stream>>>(rows, cols, vals, cursor, binned, nnz, NB);
    finalize_kernel<<<NB, 256, 0, stream>>>(base, binned, row_ptr, edges, N);

    const float4* ue4   = (const float4*)ue;
    const float4* ie4   = (const float4*)ie;
    float4* embA4 = (float4*)embA;
    float4* embB4 = (float4*)embB;
    float4* acc4  = (float4*)acc;

    int ugrid = (nu * 64 + 255) / 256;
    int igrid = (ni * 64 + 255) / 256;

    // layer 0: user rows gather item table (window 25.6MB); item rows gather
    // user table (51.2MB). cofs maps absolute col -> table-local row.
    layer_kernel<0><<<ugrid, 256, 0, stream>>>(row_ptr, edges, ie4, nu, ue4, embA4, acc4, 0,  nu);
    layer_kernel<0><<<igrid, 256, 0, stream>>>(row_ptr, edges, ue4, 0,  ie4, embA4, acc4, nu, ni);
    // layer 1
    layer_kernel<1><<<ugrid, 256, 0, stream>>>(row_ptr, edges, embA4, 0, nullptr, embB4, acc4, 0,  nu);
    layer_kernel<1><<<igrid, 256, 0, stream>>>(row_ptr, edges, embA4, 0, nullptr, embB4, acc4, nu, ni);
    // layer 2
    layer_kernel<2><<<ugrid, 256, 0, stream>>>(row_ptr, edges, embB4, 0, nullptr, nullptr, acc4, 0,  nu);
    layer_kernel<2><<<igrid, 256, 0, stream>>>(row_ptr, edges, embB4, 0, nullptr, nullptr, acc4, nu, ni);
}

// Round 4
// 1485.358 us; speedup vs baseline: 1.4675x; 1.0447x over previous
//
#include <hip/hip_runtime.h>

// LightGCN propagation: 3 sparse layers over a fixed bipartite graph.
// R6: occupancy fix on preprocessing. R5's bin_kernel was latency-bound at
// 24% occupancy (611 blocks x 4 waves = 2444 waves vs 8192 capacity;
// VALUBusy 2.5%, HBM 20%). Same grid-shape defect in coarse_hist (2048
// waves) and finalize (2344 waves). All three now run 1024 threads/block
// with unchanged chunk sizes -> identical memory behavior and atomic
// counts, 4x the latency-hiding waves.
// Layer kernels unchanged from R4/R5 (16-lane float4 gathers, phase split).

#define EMB 64
// 512 rows per bucket: localrow = 9 bits, col < 300000 -> 19 bits, packs in 28.
#define BSH 9
#define BROWS 512

__global__ __launch_bounds__(1024) void coarse_hist(const int* __restrict__ rows,
                                                    int* __restrict__ cnt, int nnz, int NB) {
    __shared__ int lcnt[1024];
    int t = threadIdx.x;
    lcnt[t] = 0;
    __syncthreads();
    int stride = gridDim.x * 1024;
    for (int i = blockIdx.x * 1024 + t; i < nnz; i += stride)
        atomicAdd(&lcnt[rows[i] >> BSH], 1);
    __syncthreads();
    int c = lcnt[t];
    if (t < NB && c > 0) atomicAdd(&cnt[t], c);
}

// single block: exclusive scan over NB (<=1024) bucket counts
__global__ void scan_buckets(const int* __restrict__ cnt, int* __restrict__ base,
                             int* __restrict__ cursor, int* __restrict__ row_ptr,
                             int NB, int N) {
    __shared__ int sblk[256];
    int t = threadIdx.x;
    int a[4]; int tsum = 0;
#pragma unroll
    for (int k = 0; k < 4; ++k) { int b = t * 4 + k; a[k] = (b < NB) ? cnt[b] : 0; tsum += a[k]; }
    int x = tsum; sblk[t] = x; __syncthreads();
    for (int off = 1; off < 256; off <<= 1) {
        int y = (t >= off) ? sblk[t - off] : 0;
        __syncthreads();
        x += y; sblk[t] = x; __syncthreads();
    }
    int run = x - tsum;   // exclusive prefix for this thread's 4 entries
#pragma unroll
    for (int k = 0; k < 4; ++k) {
        int b = t * 4 + k;
        if (b < NB) { base[b] = run; cursor[b] = run; }
        run += a[k];
    }
    if (t == 255) { base[NB] = x; row_ptr[N] = x; }   // x == nnz
}

// Bucket-grouped binning. Per block: count chunk's edges per bucket in LDS,
// reserve one contiguous range per touched bucket (1 global atomic each),
// then place records. 1024 threads x VPT 16 = chunk 16384 (same as R5's
// 256 x 64): identical run lengths and atomic counts, 4x the waves.
#define BIN_VPT 16
__global__ __launch_bounds__(1024) void bin_kernel(
    const int* __restrict__ rows, const int* __restrict__ cols,
    const float* __restrict__ vals, int* __restrict__ cursor,
    int2* __restrict__ binned, int nnz, int NB)
{
    __shared__ int lcnt[1024];
    __shared__ int gbase[1024];
    int t = threadIdx.x;
    int base0 = blockIdx.x * (1024 * BIN_VPT);
    lcnt[t] = 0;
    __syncthreads();
#pragma unroll 4
    for (int j = 0; j < BIN_VPT; ++j) {
        int i = base0 + j * 1024 + t;
        if (i < nnz) atomicAdd(&lcnt[rows[i] >> BSH], 1);
    }
    __syncthreads();
    {
        int c = lcnt[t];
        if (t < NB && c > 0) gbase[t] = atomicAdd(&cursor[t], c);
        lcnt[t] = 0;
    }
    __syncthreads();
#pragma unroll 4
    for (int j = 0; j < BIN_VPT; ++j) {
        int i = base0 + j * 1024 + t;
        if (i < nnz) {
            int r = rows[i];
            int b = r >> BSH;
            int lp = atomicAdd(&lcnt[b], 1);
            binned[gbase[b] + lp] =
                make_int2(((r - (b << BSH)) << 19) | cols[i], __float_as_int(vals[i]));
        }
    }
}

// One WG per bucket: LDS row-hist + scan -> row_ptr; then scatter records to
// final CSR slots via LDS cursors (L2-resident window, zero global atomics).
// 1024 threads; the 512-count scan runs on the first 256 threads with
// uniform barriers.
__global__ __launch_bounds__(1024) void finalize_kernel(
    const int* __restrict__ base, const int2* __restrict__ binned,
    int* __restrict__ row_ptr, int2* __restrict__ edges, int N)
{
    __shared__ int lhist[BROWS];
    __shared__ int lpref[BROWS];
    __shared__ int sblk[256];
    int b = blockIdx.x;
    int t = threadIdx.x;
    int s = base[b], e = base[b + 1];
    if (t < BROWS) lhist[t] = 0;
    __syncthreads();
    for (int i = s + t; i < e; i += 1024)
        atomicAdd(&lhist[binned[i].x >> 19], 1);
    __syncthreads();
    int a0 = 0, a1 = 0, tsum = 0, x = 0;
    if (t < 256) {
        a0 = lhist[2 * t]; a1 = lhist[2 * t + 1];
        tsum = a0 + a1; x = tsum; sblk[t] = x;
    }
    __syncthreads();
    for (int off = 1; off < 256; off <<= 1) {
        int y = (t < 256 && t >= off) ? sblk[t - off] : 0;
        __syncthreads();
        if (t < 256) { x += y; sblk[t] = x; }
        __syncthreads();
    }
    if (t < 256) { lpref[2 * t] = x - tsum; lpref[2 * t + 1] = x - tsum + a0; }
    __syncthreads();
    if (t < BROWS) {
        int gr = (b << BSH) + t;
        int slot = s + lpref[t];
        if (gr < N) row_ptr[gr] = slot;
        lhist[t] = slot;   // reuse as global-slot cursor
    }
    __syncthreads();
    for (int i = s + t; i < e; i += 1024) {
        int2 rec = binned[i];
        int lr = rec.x >> 19;
        int pos = atomicAdd(&lhist[lr], 1);
        edges[pos] = make_int2(rec.x & 0x7FFFF, rec.y);
    }
}

// One wave per row. 16-lane groups: group g (of 4) handles edge i+g, each
// lane holds 4 dims (float4). One gather instr = 4 edges' rows = 1KB.
// MODE 0: acc = init + sum; embout = sum
// MODE 1: acc += sum;        embout = sum
// MODE 2: acc = (acc + sum) * 0.25, no embout
template<int MODE>
__global__ __launch_bounds__(256) void layer_kernel(
    const int* __restrict__ row_ptr, const int2* __restrict__ edges,
    const float4* __restrict__ src4, int cofs,
    const float4* __restrict__ init4,
    float4* __restrict__ embout4, float4* __restrict__ acc4,
    int row0, int nrows)
{
    int wid = (int)((blockIdx.x * blockDim.x + threadIdx.x) >> 6);
    if (wid >= nrows) return;
    int row  = row0 + wid;
    int lane = threadIdx.x & 63;
    int grp  = lane >> 4;
    int sub  = lane & 15;
    int s = row_ptr[row], e = row_ptr[row + 1];

    float4 a0 = make_float4(0.f, 0.f, 0.f, 0.f);
    float4 a1 = make_float4(0.f, 0.f, 0.f, 0.f);
    float4 a2 = make_float4(0.f, 0.f, 0.f, 0.f);
    float4 a3 = make_float4(0.f, 0.f, 0.f, 0.f);

    int i = s;
    for (; i + 16 <= e; i += 16) {
        int2 c0 = edges[i + grp];
        int2 c1 = edges[i + 4 + grp];
        int2 c2 = edges[i + 8 + grp];
        int2 c3 = edges[i + 12 + grp];
        float4 g0 = src4[(size_t)(c0.x - cofs) * 16 + sub];
        float4 g1 = src4[(size_t)(c1.x - cofs) * 16 + sub];
        float4 g2 = src4[(size_t)(c2.x - cofs) * 16 + sub];
        float4 g3 = src4[(size_t)(c3.x - cofs) * 16 + sub];
        float v0 = __int_as_float(c0.y);
        float v1 = __int_as_float(c1.y);
        float v2 = __int_as_float(c2.y);
        float v3 = __int_as_float(c3.y);
        a0.x = fmaf(v0, g0.x, a0.x); a0.y = fmaf(v0, g0.y, a0.y);
        a0.z = fmaf(v0, g0.z, a0.z); a0.w = fmaf(v0, g0.w, a0.w);
        a1.x = fmaf(v1, g1.x, a1.x); a1.y = fmaf(v1, g1.y, a1.y);
        a1.z = fmaf(v1, g1.z, a1.z); a1.w = fmaf(v1, g1.w, a1.w);
        a2.x = fmaf(v2, g2.x, a2.x); a2.y = fmaf(v2, g2.y, a2.y);
        a2.z = fmaf(v2, g2.z, a2.z); a2.w = fmaf(v2, g2.w, a2.w);
        a3.x = fmaf(v3, g3.x, a3.x); a3.y = fmaf(v3, g3.y, a3.y);
        a3.z = fmaf(v3, g3.z, a3.z); a3.w = fmaf(v3, g3.w, a3.w);
    }
    for (; i < e; i += 4) {
        int j = i + grp;
        if (j < e) {
            int2 cv = edges[j];
            float4 g = src4[(size_t)(cv.x - cofs) * 16 + sub];
            float v = __int_as_float(cv.y);
            a0.x = fmaf(v, g.x, a0.x); a0.y = fmaf(v, g.y, a0.y);
            a0.z = fmaf(v, g.z, a0.z); a0.w = fmaf(v, g.w, a0.w);
        }
    }

    float4 t;
    t.x = (a0.x + a1.x) + (a2.x + a3.x);
    t.y = (a0.y + a1.y) + (a2.y + a3.y);
    t.z = (a0.z + a1.z) + (a2.z + a3.z);
    t.w = (a0.w + a1.w) + (a2.w + a3.w);
    t.x += __shfl_xor(t.x, 16); t.x += __shfl_xor(t.x, 32);
    t.y += __shfl_xor(t.y, 16); t.y += __shfl_xor(t.y, 32);
    t.z += __shfl_xor(t.z, 16); t.z += __shfl_xor(t.z, 32);
    t.w += __shfl_xor(t.w, 16); t.w += __shfl_xor(t.w, 32);

    if (grp == 0) {
        size_t o = (size_t)row * 16 + sub;
        if (MODE != 2) embout4[o] = t;
        if (MODE == 0) {
            float4 b = init4[(size_t)wid * 16 + sub];
            b.x += t.x; b.y += t.y; b.z += t.z; b.w += t.w;
            acc4[o] = b;
        } else if (MODE == 1) {
            float4 r = acc4[o];
            r.x += t.x; r.y += t.y; r.z += t.z; r.w += t.w;
            acc4[o] = r;
        } else {
            float4 r = acc4[o];
            r.x = (r.x + t.x) * 0.25f; r.y = (r.y + t.y) * 0.25f;
            r.z = (r.z + t.z) * 0.25f; r.w = (r.w + t.w) * 0.25f;
            acc4[o] = r;
        }
    }
}

extern "C" void kernel_launch(void* const* d_in, const int* in_sizes, int n_in,
                              void* d_out, int out_size, void* d_ws, size_t ws_size,
                              hipStream_t stream) {
    const float* ue   = (const float*)d_in[0];
    const float* ie   = (const float*)d_in[1];
    const float* vals = (const float*)d_in[2];
    const int*   rows = (const int*)d_in[3];
    const int*   cols = (const int*)d_in[4];

    int nu  = in_sizes[0] / EMB;
    int ni  = in_sizes[1] / EMB;
    int N   = nu + ni;
    int nnz = in_sizes[2];
    int M   = N + 1;
    int NB  = (N + BROWS - 1) >> BSH;   // 586 buckets for N=300000 (<=1024)

    // workspace carve-out (256B aligned)
    char*  w   = (char*)d_ws;
    size_t off = 0;
    auto alloc = [&](size_t bytes) -> void* {
        void* p = w + off;
        off = (off + bytes + 255) & ~(size_t)255;
        return p;
    };
    float* embA    = (float*)alloc((size_t)N * EMB * sizeof(float));
    float* embB    = (float*)alloc((size_t)N * EMB * sizeof(float));
    int2*  edges   = (int2*) alloc((size_t)nnz * sizeof(int2));
    int*   cnt     = (int*)  alloc(1024 * sizeof(int));
    int*   base    = (int*)  alloc(1025 * sizeof(int));
    int*   cursor  = (int*)  alloc(1024 * sizeof(int));
    int*   row_ptr = (int*)  alloc((size_t)M * sizeof(int));
    float* acc     = (float*)d_out;   // accumulator lives in the output buffer

    // binned records (nnz * 8B = 80MB) alias embA+embB (153.6MB), which are
    // dead until layer0 runs (after finalize_kernel has consumed binned).
    int2* binned = (int2*)embA;

    hipMemsetAsync(cnt, 0, 1024 * sizeof(int), stream);

    coarse_hist<<<512, 1024, 0, stream>>>(rows, cnt, nnz, NB);
    scan_buckets<<<1, 256, 0, stream>>>(cnt, base, cursor, row_ptr, NB, N);

    int bgrid = (nnz + 1024 * BIN_VPT - 1) / (1024 * BIN_VPT);
    bin_kernel<<<bgrid, 1024, 0, stream>>>(rows, cols, vals, cursor, binned, nnz, NB);
    finalize_kernel<<<NB, 1024, 0, stream>>>(base, binned, row_ptr, edges, N);

    const float4* ue4   = (const float4*)ue;
    const float4* ie4   = (const float4*)ie;
    float4* embA4 = (float4*)embA;
    float4* embB4 = (float4*)embB;
    float4* acc4  = (float4*)acc;

    int ugrid = (nu * 64 + 255) / 256;
    int igrid = (ni * 64 + 255) / 256;

    // layer 0: user rows gather item table; item rows gather user table.
    layer_kernel<0><<<ugrid, 256, 0, stream>>>(row_ptr, edges, ie4, nu, ue4, embA4, acc4, 0,  nu);
    layer_kernel<0><<<igrid, 256, 0, stream>>>(row_ptr, edges, ue4, 0,  ie4, embA4, acc4, nu, ni);
    // layer 1
    layer_kernel<1><<<ugrid, 256, 0, stream>>>(row_ptr, edges, embA4, 0, nullptr, embB4, acc4, 0,  nu);
    layer_kernel<1><<<igrid, 256, 0, stream>>>(row_ptr, edges, embA4, 0, nullptr, embB4, acc4, nu, ni);
    // layer 2
    layer_kernel<2><<<ugrid, 256, 0, stream>>>(row_ptr, edges, embB4, 0, nullptr, nullptr, acc4, 0,  nu);
    layer_kernel<2><<<igrid, 256, 0, stream>>>(row_ptr, edges, embB4, 0, nullptr, nullptr, acc4, nu, ni);
}

// Round 5
// 1450.245 us; speedup vs baseline: 1.5031x; 1.0242x over previous
//
#include <hip/hip_runtime.h>

// LightGCN propagation: 3 sparse layers over a fixed bipartite graph.
// R7: layer-kernel refinements (preprocessing unchanged from R6):
//  (a) predicated 16-edge tail tile: clamp index to e-1, zero the weight for
//      j>=e -> uniform 4-gathers-in-flight MLP everywhere. R6's serial tail
//      (1 gather in flight) covered ~36% of user-phase edges (deg~25).
//  (b) acc recomposition: acc = 0.25*(e0 + embA + embB + sum) computed only
//      in layer 2. Kills MODE0 acc-write + init-read and MODE1 acc RMW
//      (-154MB stream traffic, no dependent RMW in layers 0/1).

#define EMB 64
// 512 rows per bucket: localrow = 9 bits, col < 300000 -> 19 bits, packs in 28.
#define BSH 9
#define BROWS 512

__global__ __launch_bounds__(1024) void coarse_hist(const int* __restrict__ rows,
                                                    int* __restrict__ cnt, int nnz, int NB) {
    __shared__ int lcnt[1024];
    int t = threadIdx.x;
    lcnt[t] = 0;
    __syncthreads();
    int stride = gridDim.x * 1024;
    for (int i = blockIdx.x * 1024 + t; i < nnz; i += stride)
        atomicAdd(&lcnt[rows[i] >> BSH], 1);
    __syncthreads();
    int c = lcnt[t];
    if (t < NB && c > 0) atomicAdd(&cnt[t], c);
}

// single block: exclusive scan over NB (<=1024) bucket counts
__global__ void scan_buckets(const int* __restrict__ cnt, int* __restrict__ base,
                             int* __restrict__ cursor, int* __restrict__ row_ptr,
                             int NB, int N) {
    __shared__ int sblk[256];
    int t = threadIdx.x;
    int a[4]; int tsum = 0;
#pragma unroll
    for (int k = 0; k < 4; ++k) { int b = t * 4 + k; a[k] = (b < NB) ? cnt[b] : 0; tsum += a[k]; }
    int x = tsum; sblk[t] = x; __syncthreads();
    for (int off = 1; off < 256; off <<= 1) {
        int y = (t >= off) ? sblk[t - off] : 0;
        __syncthreads();
        x += y; sblk[t] = x; __syncthreads();
    }
    int run = x - tsum;   // exclusive prefix for this thread's 4 entries
#pragma unroll
    for (int k = 0; k < 4; ++k) {
        int b = t * 4 + k;
        if (b < NB) { base[b] = run; cursor[b] = run; }
        run += a[k];
    }
    if (t == 255) { base[NB] = x; row_ptr[N] = x; }   // x == nnz
}

// Bucket-grouped binning: count chunk's edges per bucket in LDS, reserve one
// contiguous range per touched bucket, place records. 1024 thr x VPT 16.
#define BIN_VPT 16
__global__ __launch_bounds__(1024) void bin_kernel(
    const int* __restrict__ rows, const int* __restrict__ cols,
    const float* __restrict__ vals, int* __restrict__ cursor,
    int2* __restrict__ binned, int nnz, int NB)
{
    __shared__ int lcnt[1024];
    __shared__ int gbase[1024];
    int t = threadIdx.x;
    int base0 = blockIdx.x * (1024 * BIN_VPT);
    lcnt[t] = 0;
    __syncthreads();
#pragma unroll 4
    for (int j = 0; j < BIN_VPT; ++j) {
        int i = base0 + j * 1024 + t;
        if (i < nnz) atomicAdd(&lcnt[rows[i] >> BSH], 1);
    }
    __syncthreads();
    {
        int c = lcnt[t];
        if (t < NB && c > 0) gbase[t] = atomicAdd(&cursor[t], c);
        lcnt[t] = 0;
    }
    __syncthreads();
#pragma unroll 4
    for (int j = 0; j < BIN_VPT; ++j) {
        int i = base0 + j * 1024 + t;
        if (i < nnz) {
            int r = rows[i];
            int b = r >> BSH;
            int lp = atomicAdd(&lcnt[b], 1);
            binned[gbase[b] + lp] =
                make_int2(((r - (b << BSH)) << 19) | cols[i], __float_as_int(vals[i]));
        }
    }
}

// One WG per bucket: LDS row-hist + scan -> row_ptr; scatter to final CSR
// slots via LDS cursors (L2-resident window, zero global atomics).
__global__ __launch_bounds__(1024) void finalize_kernel(
    const int* __restrict__ base, const int2* __restrict__ binned,
    int* __restrict__ row_ptr, int2* __restrict__ edges, int N)
{
    __shared__ int lhist[BROWS];
    __shared__ int lpref[BROWS];
    __shared__ int sblk[256];
    int b = blockIdx.x;
    int t = threadIdx.x;
    int s = base[b], e = base[b + 1];
    if (t < BROWS) lhist[t] = 0;
    __syncthreads();
    for (int i = s + t; i < e; i += 1024)
        atomicAdd(&lhist[binned[i].x >> 19], 1);
    __syncthreads();
    int a0 = 0, a1 = 0, tsum = 0, x = 0;
    if (t < 256) {
        a0 = lhist[2 * t]; a1 = lhist[2 * t + 1];
        tsum = a0 + a1; x = tsum; sblk[t] = x;
    }
    __syncthreads();
    for (int off = 1; off < 256; off <<= 1) {
        int y = (t < 256 && t >= off) ? sblk[t - off] : 0;
        __syncthreads();
        if (t < 256) { x += y; sblk[t] = x; }
        __syncthreads();
    }
    if (t < 256) { lpref[2 * t] = x - tsum; lpref[2 * t + 1] = x - tsum + a0; }
    __syncthreads();
    if (t < BROWS) {
        int gr = (b << BSH) + t;
        int slot = s + lpref[t];
        if (gr < N) row_ptr[gr] = slot;
        lhist[t] = slot;   // reuse as global-slot cursor
    }
    __syncthreads();
    for (int i = s + t; i < e; i += 1024) {
        int2 rec = binned[i];
        int lr = rec.x >> 19;
        int pos = atomicAdd(&lhist[lr], 1);
        edges[pos] = make_int2(rec.x & 0x7FFFF, rec.y);
    }
}

// One wave per row. 16-lane groups: group g handles edge i+g (+4,+8,+12),
// each lane holds 4 dims (float4): one gather instr = 4 edges' rows = 1KB.
// Main loop unpredicated; single predicated tail tile keeps MLP-4.
// MODE 0: embout = sum (gather from opposite table, table-local via cofs)
// MODE 1: embout = sum (gather from embA)
// MODE 2: acc = 0.25*(init + prev + own + sum)  (gather from embB)
template<int MODE>
__global__ __launch_bounds__(256) void layer_kernel(
    const int* __restrict__ row_ptr, const int2* __restrict__ edges,
    const float4* __restrict__ src4, int cofs,
    const float4* __restrict__ init4, const float4* __restrict__ prev4,
    float4* __restrict__ embout4, float4* __restrict__ acc4,
    int row0, int nrows)
{
    int wid = (int)((blockIdx.x * blockDim.x + threadIdx.x) >> 6);
    if (wid >= nrows) return;
    int row  = row0 + wid;
    int lane = threadIdx.x & 63;
    int grp  = lane >> 4;
    int sub  = lane & 15;
    int s = row_ptr[row], e = row_ptr[row + 1];

    float4 a0 = make_float4(0.f, 0.f, 0.f, 0.f);
    float4 a1 = make_float4(0.f, 0.f, 0.f, 0.f);
    float4 a2 = make_float4(0.f, 0.f, 0.f, 0.f);
    float4 a3 = make_float4(0.f, 0.f, 0.f, 0.f);

    int i = s;
    for (; i + 16 <= e; i += 16) {
        int2 c0 = edges[i + grp];
        int2 c1 = edges[i + 4 + grp];
        int2 c2 = edges[i + 8 + grp];
        int2 c3 = edges[i + 12 + grp];
        float4 g0 = src4[(size_t)(c0.x - cofs) * 16 + sub];
        float4 g1 = src4[(size_t)(c1.x - cofs) * 16 + sub];
        float4 g2 = src4[(size_t)(c2.x - cofs) * 16 + sub];
        float4 g3 = src4[(size_t)(c3.x - cofs) * 16 + sub];
        float v0 = __int_as_float(c0.y);
        float v1 = __int_as_float(c1.y);
        float v2 = __int_as_float(c2.y);
        float v3 = __int_as_float(c3.y);
        a0.x = fmaf(v0, g0.x, a0.x); a0.y = fmaf(v0, g0.y, a0.y);
        a0.z = fmaf(v0, g0.z, a0.z); a0.w = fmaf(v0, g0.w, a0.w);
        a1.x = fmaf(v1, g1.x, a1.x); a1.y = fmaf(v1, g1.y, a1.y);
        a1.z = fmaf(v1, g1.z, a1.z); a1.w = fmaf(v1, g1.w, a1.w);
        a2.x = fmaf(v2, g2.x, a2.x); a2.y = fmaf(v2, g2.y, a2.y);
        a2.z = fmaf(v2, g2.z, a2.z); a2.w = fmaf(v2, g2.w, a2.w);
        a3.x = fmaf(v3, g3.x, a3.x); a3.y = fmaf(v3, g3.y, a3.y);
        a3.z = fmaf(v3, g3.z, a3.z); a3.w = fmaf(v3, g3.w, a3.w);
    }
    if (i < e) {
        // predicated tail tile: clamp index (address stays valid), zero weight
        int e1 = e - 1;
        int j0 = i + grp, j1 = j0 + 4, j2 = j0 + 8, j3 = j0 + 12;
        int2 c0 = edges[min(j0, e1)];
        int2 c1 = edges[min(j1, e1)];
        int2 c2 = edges[min(j2, e1)];
        int2 c3 = edges[min(j3, e1)];
        float4 g0 = src4[(size_t)(c0.x - cofs) * 16 + sub];
        float4 g1 = src4[(size_t)(c1.x - cofs) * 16 + sub];
        float4 g2 = src4[(size_t)(c2.x - cofs) * 16 + sub];
        float4 g3 = src4[(size_t)(c3.x - cofs) * 16 + sub];
        float v0 = (j0 < e) ? __int_as_float(c0.y) : 0.f;
        float v1 = (j1 < e) ? __int_as_float(c1.y) : 0.f;
        float v2 = (j2 < e) ? __int_as_float(c2.y) : 0.f;
        float v3 = (j3 < e) ? __int_as_float(c3.y) : 0.f;
        a0.x = fmaf(v0, g0.x, a0.x); a0.y = fmaf(v0, g0.y, a0.y);
        a0.z = fmaf(v0, g0.z, a0.z); a0.w = fmaf(v0, g0.w, a0.w);
        a1.x = fmaf(v1, g1.x, a1.x); a1.y = fmaf(v1, g1.y, a1.y);
        a1.z = fmaf(v1, g1.z, a1.z); a1.w = fmaf(v1, g1.w, a1.w);
        a2.x = fmaf(v2, g2.x, a2.x); a2.y = fmaf(v2, g2.y, a2.y);
        a2.z = fmaf(v2, g2.z, a2.z); a2.w = fmaf(v2, g2.w, a2.w);
        a3.x = fmaf(v3, g3.x, a3.x); a3.y = fmaf(v3, g3.y, a3.y);
        a3.z = fmaf(v3, g3.z, a3.z); a3.w = fmaf(v3, g3.w, a3.w);
    }

    float4 t;
    t.x = (a0.x + a1.x) + (a2.x + a3.x);
    t.y = (a0.y + a1.y) + (a2.y + a3.y);
    t.z = (a0.z + a1.z) + (a2.z + a3.z);
    t.w = (a0.w + a1.w) + (a2.w + a3.w);
    t.x += __shfl_xor(t.x, 16); t.x += __shfl_xor(t.x, 32);
    t.y += __shfl_xor(t.y, 16); t.y += __shfl_xor(t.y, 32);
    t.z += __shfl_xor(t.z, 16); t.z += __shfl_xor(t.z, 32);
    t.w += __shfl_xor(t.w, 16); t.w += __shfl_xor(t.w, 32);

    if (grp == 0) {
        size_t o = (size_t)row * 16 + sub;
        if (MODE != 2) {
            embout4[o] = t;
        } else {
            float4 b  = init4[(size_t)wid * 16 + sub];   // e0 (table-local)
            float4 pa = prev4[o];                        // e1 = embA
            float4 pb = src4[o];                         // e2 = embB (own row)
            float4 r;
            r.x = 0.25f * (((b.x + pa.x) + pb.x) + t.x);
            r.y = 0.25f * (((b.y + pa.y) + pb.y) + t.y);
            r.z = 0.25f * (((b.z + pa.z) + pb.z) + t.z);
            r.w = 0.25f * (((b.w + pa.w) + pb.w) + t.w);
            acc4[o] = r;
        }
    }
}

extern "C" void kernel_launch(void* const* d_in, const int* in_sizes, int n_in,
                              void* d_out, int out_size, void* d_ws, size_t ws_size,
                              hipStream_t stream) {
    const float* ue   = (const float*)d_in[0];
    const float* ie   = (const float*)d_in[1];
    const float* vals = (const float*)d_in[2];
    const int*   rows = (const int*)d_in[3];
    const int*   cols = (const int*)d_in[4];

    int nu  = in_sizes[0] / EMB;
    int ni  = in_sizes[1] / EMB;
    int N   = nu + ni;
    int nnz = in_sizes[2];
    int M   = N + 1;
    int NB  = (N + BROWS - 1) >> BSH;   // 586 buckets for N=300000 (<=1024)

    // workspace carve-out (256B aligned)
    char*  w   = (char*)d_ws;
    size_t off = 0;
    auto alloc = [&](size_t bytes) -> void* {
        void* p = w + off;
        off = (off + bytes + 255) & ~(size_t)255;
        return p;
    };
    float* embA    = (float*)alloc((size_t)N * EMB * sizeof(float));
    float* embB    = (float*)alloc((size_t)N * EMB * sizeof(float));
    int2*  edges   = (int2*) alloc((size_t)nnz * sizeof(int2));
    int*   cnt     = (int*)  alloc(1024 * sizeof(int));
    int*   base    = (int*)  alloc(1025 * sizeof(int));
    int*   cursor  = (int*)  alloc(1024 * sizeof(int));
    int*   row_ptr = (int*)  alloc((size_t)M * sizeof(int));
    float* acc     = (float*)d_out;   // final output

    // binned records (nnz * 8B = 80MB) alias embA+embB (153.6MB), which are
    // dead until layer0 runs (after finalize_kernel has consumed binned).
    int2* binned = (int2*)embA;

    hipMemsetAsync(cnt, 0, 1024 * sizeof(int), stream);

    coarse_hist<<<512, 1024, 0, stream>>>(rows, cnt, nnz, NB);
    scan_buckets<<<1, 256, 0, stream>>>(cnt, base, cursor, row_ptr, NB, N);

    int bgrid = (nnz + 1024 * BIN_VPT - 1) / (1024 * BIN_VPT);
    bin_kernel<<<bgrid, 1024, 0, stream>>>(rows, cols, vals, cursor, binned, nnz, NB);
    finalize_kernel<<<NB, 1024, 0, stream>>>(base, binned, row_ptr, edges, N);

    const float4* ue4   = (const float4*)ue;
    const float4* ie4   = (const float4*)ie;
    float4* embA4 = (float4*)embA;
    float4* embB4 = (float4*)embB;
    float4* acc4  = (float4*)acc;

    int ugrid = (nu * 64 + 255) / 256;
    int igrid = (ni * 64 + 255) / 256;

    // layer 0: user rows gather item table; item rows gather user table.
    layer_kernel<0><<<ugrid, 256, 0, stream>>>(row_ptr, edges, ie4, nu, nullptr, nullptr, embA4, nullptr, 0,  nu);
    layer_kernel<0><<<igrid, 256, 0, stream>>>(row_ptr, edges, ue4, 0,  nullptr, nullptr, embA4, nullptr, nu, ni);
    // layer 1
    layer_kernel<1><<<ugrid, 256, 0, stream>>>(row_ptr, edges, embA4, 0, nullptr, nullptr, embB4, nullptr, 0,  nu);
    layer_kernel<1><<<igrid, 256, 0, stream>>>(row_ptr, edges, embA4, 0, nullptr, nullptr, embB4, nullptr, nu, ni);
    // layer 2: acc = 0.25*(e0 + embA + embB + sum)
    layer_kernel<2><<<ugrid, 256, 0, stream>>>(row_ptr, edges, embB4, 0, ue4, embA4, nullptr, acc4, 0,  nu);
    layer_kernel<2><<<igrid, 256, 0, stream>>>(row_ptr, edges, embB4, 0, ie4, embA4, nullptr, acc4, nu, ni);
}